// Round 14
// baseline (169.408 us; speedup 1.0000x reference)
//
#include <hip/hip_runtime.h>
#include <math.h>

#define D_MODEL 256
#define N_HEADS 8
#define HEAD_DIM 32
#define D_FFN   1024
#define BB      4
#define NN      1024
#define M_TOT   (BB * NN)     // 4096 rows
#define LN_EPS  1e-5f

// scale = 1/sqrt(32); baked into qb:  scale * log2(e)
#define QSCALE_LOG2E 0.2550348612f
#define LOG2E        1.4426950408889634f

typedef float f32x4 __attribute__((ext_vector_type(4)));
typedef short bf16x8 __attribute__((ext_vector_type(8)));

__device__ __forceinline__ unsigned short f2bf(float f) {
    unsigned int u = __float_as_uint(f);
    unsigned int r = (u + 0x7fffu + ((u >> 16) & 1u)) >> 16;
    return (unsigned short)r;
}
__device__ __forceinline__ ushort4 pack4(float4 v) {
    ushort4 o; o.x = f2bf(v.x); o.y = f2bf(v.y); o.z = f2bf(v.z); o.w = f2bf(v.w);
    return o;
}
__device__ __forceinline__ float fast_exp2(float x) {
#if __has_builtin(__builtin_amdgcn_exp2f)
    return __builtin_amdgcn_exp2f(x);
#else
    return exp2f(x);
#endif
}
__device__ __forceinline__ float bf2f(unsigned short s) {
    return __uint_as_float(((unsigned int)s) << 16);
}

// ---------------------------------------------------------------------------
// K1: fused prep.
//  blocks [0,1024):    emb_bf / qk_bf activations
//  blocks [1024,1216): inw fp32->bf16 (row-major, for qkv)
//  blocks [1216,1504): outw/w1/w2 -> WAVE-FRAGMENT layout bf16 (1 KB/instr
//                      streams in post)
//  blocks [1504,1520): zero-padded tau tile
// ---------------------------------------------------------------------------
__global__ __launch_bounds__(256)
void prep_all_kernel(const float4* __restrict__ e, const float4* __restrict__ qp,
                     ushort4* __restrict__ ebf, ushort4* __restrict__ qkbf,
                     const float4* __restrict__ inw4, ushort4* __restrict__ o_inw,
                     const float* __restrict__ outw, const float* __restrict__ w1,
                     const float* __restrict__ w2,
                     unsigned short* __restrict__ o_outwf,
                     unsigned short* __restrict__ o_w1f,
                     unsigned short* __restrict__ o_w2f,
                     const float4* __restrict__ tauw, ushort4* __restrict__ o_taupad) {
    if (blockIdx.x < 1024) {
        int i = blockIdx.x * 256 + threadIdx.x;       // < 262144
        float4 ev = e[i], pv = qp[i];
        ebf[i] = pack4(ev);
        float4 s = make_float4(ev.x + pv.x, ev.y + pv.y, ev.z + pv.z, ev.w + pv.w);
        qkbf[i] = pack4(s);
    } else if (blockIdx.x < 1216) {
        int i = (blockIdx.x - 1024) * 256 + threadIdx.x;   // < 49152
        o_inw[i] = pack4(inw4[i]);
    } else if (blockIdx.x < 1504) {
        int fid = (blockIdx.x - 1216) * 256 + threadIdx.x; // < 73728
        const float* W; unsigned short* dst; int K;
        if (fid < 8192)       { W = outw; dst = o_outwf; K = 256; }
        else if (fid < 40960) { W = w1;   dst = o_w1f;   K = 256;  fid -= 8192; }
        else                  { W = w2;   dst = o_w2f;   K = 1024; fid -= 40960; }
        const int lane = fid & 63;
        const int t = fid >> 6;
        const int kk = t % (K / 32);
        const int n16 = t / (K / 32);
        const int row = n16 * 16 + (lane & 15);
        const int col = kk * 32 + (lane >> 4) * 8;
        const float* src = &W[(size_t)row * K + col];
        float4 s0 = *(const float4*)src, s1 = *(const float4*)(src + 4);
        *(ushort4*)&dst[(size_t)fid * 8]     = pack4(s0);
        *(ushort4*)&dst[(size_t)fid * 8 + 4] = pack4(s1);
    } else {
        int q = (blockIdx.x - 1504) * 256 + threadIdx.x;   // < 4096
        if (q < 512) o_taupad[q] = pack4(tauw[q]);
        else { ushort4 z = {0, 0, 0, 0}; o_taupad[q] = z; }
    }
}

// ---------------------------------------------------------------------------
// K2: qkv+tau register-direct MFMA GEMM (bf16 pre-staged A).
// q stored pre-scaled by scale*log2e; tau pre-scaled by log2e (exp2 path).
// ---------------------------------------------------------------------------
__global__ __launch_bounds__(256)
void qkv_mfma_kernel(const unsigned short* __restrict__ qk_bf,
                     const unsigned short* __restrict__ emb_bf,
                     const unsigned short* __restrict__ inw_bf,
                     const unsigned short* __restrict__ taupad,
                     const float* __restrict__ in_proj_b, const float* __restrict__ tau_b,
                     unsigned short* __restrict__ qb, unsigned short* __restrict__ kb,
                     unsigned short* __restrict__ vbT, float* __restrict__ taub) {
    const int w    = threadIdx.x >> 6;
    const int lane = threadIdx.x & 63;
    const int l16 = lane & 15, l4 = lane >> 4;
    const int n0 = blockIdx.x * 64;
    const int m0 = blockIdx.y * 64;
    const int wm = (w >> 1) * 32, wn = (w & 1) * 32;

    const unsigned short* A = (blockIdx.x < 8) ? qk_bf : emb_bf;
    const unsigned short* W0 = (n0 < 768) ? &inw_bf[(size_t)(n0 + wn + l16) * D_MODEL]
                                          : &taupad[(size_t)(wn + l16) * D_MODEL];
    const unsigned short* Ar0 = &A[(size_t)(m0 + wm + l16) * D_MODEL];

    f32x4 acc[2][2] = {};
    #pragma unroll
    for (int k0 = 0; k0 < D_MODEL; k0 += 32) {
        bf16x8 a0 = *(const bf16x8*)&Ar0[k0 + l4 * 8];
        bf16x8 a1 = *(const bf16x8*)&Ar0[16 * D_MODEL + k0 + l4 * 8];
        bf16x8 b0 = *(const bf16x8*)&W0[k0 + l4 * 8];
        bf16x8 b1 = *(const bf16x8*)&W0[16 * D_MODEL + k0 + l4 * 8];
        acc[0][0] = __builtin_amdgcn_mfma_f32_16x16x32_bf16(a0, b0, acc[0][0], 0, 0, 0);
        acc[0][1] = __builtin_amdgcn_mfma_f32_16x16x32_bf16(a0, b1, acc[0][1], 0, 0, 0);
        acc[1][0] = __builtin_amdgcn_mfma_f32_16x16x32_bf16(a1, b0, acc[1][0], 0, 0, 0);
        acc[1][1] = __builtin_amdgcn_mfma_f32_16x16x32_bf16(a1, b1, acc[1][1], 0, 0, 0);
    }

    #pragma unroll
    for (int i = 0; i < 2; i++) {
        #pragma unroll
        for (int j = 0; j < 2; j++) {
            #pragma unroll
            for (int r = 0; r < 4; r++) {
                const int m = m0 + wm + i * 16 + l4 * 4 + r;
                const int b = m >> 10, nrow = m & 1023;
                const int c = n0 + wn + j * 16 + l16;
                float v = acc[i][j][r];
                if (c < 256) {
                    v = (v + in_proj_b[c]) * QSCALE_LOG2E;   // pre-scaled q
                    int h = c >> 5, d = c & 31;
                    qb[((size_t)(b * N_HEADS + h) * NN + nrow) * HEAD_DIM + d] = f2bf(v);
                } else if (c < 512) {
                    v += in_proj_b[c];
                    int cc = c - 256; int h = cc >> 5, d = cc & 31;
                    kb[((size_t)(b * N_HEADS + h) * NN + nrow) * HEAD_DIM + d] = f2bf(v);
                } else if (c < 768) {
                    v += in_proj_b[c];
                    int cc = c - 512; int h = cc >> 5, d = cc & 31;
                    vbT[((size_t)(b * N_HEADS + h) * HEAD_DIM + d) * NN + nrow] = f2bf(v);
                } else if (c < 776) {
                    v = (v + tau_b[c - 768]) * LOG2E;        // pre-scaled tau
                    taub[(size_t)(b * N_HEADS + (c - 768)) * NN + nrow] = v;
                }
            }
        }
    }
}

// ---------------------------------------------------------------------------
// K3: flash MFMA attention v3. Split-K x2 (512 keys/block) with two-half
// LDS staging: same 41 KB footprint, staging traffic + Opart I/O halved vs
// z=4, block-ramp count halved. Interleaved key mapping, unnormalized exp2,
// bf16 Opart.
// ---------------------------------------------------------------------------
__global__ __launch_bounds__(256)
void attn_mfma_kernel(const unsigned short* __restrict__ qb,
                      const unsigned short* __restrict__ kb,
                      const unsigned short* __restrict__ vbT,
                      const float* __restrict__ taub,
                      const float* __restrict__ dist,
                      unsigned short* __restrict__ Opart,
                      float* __restrict__ lpart) {
    __shared__ unsigned short Kf[4][4][512];       // [kt][s][lane*8]       16 KB
    __shared__ unsigned short Vf[4][2][2][512];    // [kt][c][half][lane*8] 16 KB
    __shared__ unsigned short Plds[4][16 * 72];    // per-wave P            9 KB
    const int w    = threadIdx.x >> 6;
    const int lane = threadIdx.x & 63;
    const int l16  = lane & 15;
    const int l4   = lane >> 4;
    const int bh = blockIdx.y;
    const int b = bh >> 3;
    const int z = blockIdx.z;
    const int i0 = blockIdx.x * 64 + w * 16;
    const int jbase = z * 512;

    // ---- stage half 0: wave w loads key-tile kt = w (keys jbase + w*64) ----
    {
        const unsigned short* kb_z = &kb[((size_t)bh * NN + jbase + w * 64) * HEAD_DIM];
        #pragma unroll
        for (int s = 0; s < 4; s++) {
            bf16x8 kv = *(const bf16x8*)&kb_z[(size_t)(l16 * 4 + s) * HEAD_DIM + l4 * 8];
            *(bf16x8*)&Kf[w][s][lane * 8] = kv;
        }
        const unsigned short* vb_z = &vbT[(size_t)bh * HEAD_DIM * NN + jbase + w * 64];
        #pragma unroll
        for (int c = 0; c < 2; c++)
            #pragma unroll
            for (int h2 = 0; h2 < 2; h2++) {
                bf16x8 vv = *(const bf16x8*)&vb_z[(size_t)(h2 * 16 + l16) * NN + c * 32 + l4 * 8];
                *(bf16x8*)&Vf[w][c][h2][lane * 8] = vv;
            }
    }

    const f32x4 zero = {0.f, 0.f, 0.f, 0.f};
    bf16x8 qf = *(const bf16x8*)&qb[((size_t)bh * NN + i0 + l16) * HEAD_DIM + l4 * 8];
    float tau_r[4];
    const float* drow[4];
    #pragma unroll
    for (int r = 0; r < 4; r++) {
        tau_r[r] = taub[(size_t)bh * NN + i0 + l4 * 4 + r];
        drow[r] = &dist[((size_t)b * NN + i0 + l4 * 4 + r) * NN + jbase];
    }
    float l_acc[4] = {0.f, 0.f, 0.f, 0.f};
    f32x4 O0 = zero, O1 = zero;
    unsigned short* pw = &Plds[w][0];

    __syncthreads();

    for (int half = 0; half < 2; half++) {
        const int hb = half * 256;
        if (half) {
            __syncthreads();   // all waves done with half-0 Kf/Vf
            const unsigned short* kb_z = &kb[((size_t)bh * NN + jbase + 256 + w * 64) * HEAD_DIM];
            #pragma unroll
            for (int s = 0; s < 4; s++) {
                bf16x8 kv = *(const bf16x8*)&kb_z[(size_t)(l16 * 4 + s) * HEAD_DIM + l4 * 8];
                *(bf16x8*)&Kf[w][s][lane * 8] = kv;
            }
            const unsigned short* vb_z = &vbT[(size_t)bh * HEAD_DIM * NN + jbase + 256 + w * 64];
            #pragma unroll
            for (int c = 0; c < 2; c++)
                #pragma unroll
                for (int h2 = 0; h2 < 2; h2++) {
                    bf16x8 vv = *(const bf16x8*)&vb_z[(size_t)(h2 * 16 + l16) * NN + c * 32 + l4 * 8];
                    *(bf16x8*)&Vf[w][c][h2][lane * 8] = vv;
                }
            __syncthreads();
        }

        for (int kt = 0; kt < 4; kt++) {
            const int j0 = hb + kt * 64;
            // dist: one float4 per r (keys l16*4 .. +3)
            f32x4 dd4[4];
            #pragma unroll
            for (int r = 0; r < 4; r++)
                dd4[r] = *(const f32x4*)&drow[r][j0 + l16 * 4];

            float parr[4][4];
            #pragma unroll
            for (int s = 0; s < 4; s++) {
                bf16x8 kfr = *(const bf16x8*)&Kf[kt][s][lane * 8];
                f32x4 S = __builtin_amdgcn_mfma_f32_16x16x32_bf16(qf, kfr, zero, 0, 0, 0);
                #pragma unroll
                for (int r = 0; r < 4; r++) {
                    const float p = fast_exp2(S[r] + dd4[r][s] * tau_r[r]);
                    parr[s][r] = p;
                    l_acc[r] += p;
                }
            }

            // P: key for (s, lane l16) is j0 + l16*4 + s -> 4 consecutive u16
            #pragma unroll
            for (int r = 0; r < 4; r++) {
                ushort4 pk;
                pk.x = f2bf(parr[0][r]); pk.y = f2bf(parr[1][r]);
                pk.z = f2bf(parr[2][r]); pk.w = f2bf(parr[3][r]);
                *(ushort4*)&pw[(l4 * 4 + r) * 72 + l16 * 4] = pk;
            }
            asm volatile("s_waitcnt lgkmcnt(0)" ::: "memory");  // wave-local RAW drain
            #pragma unroll
            for (int c = 0; c < 2; c++) {
                bf16x8 pf = *(const bf16x8*)&pw[l16 * 72 + c * 32 + l4 * 8];
                bf16x8 v0 = *(const bf16x8*)&Vf[kt][c][0][lane * 8];
                bf16x8 v1 = *(const bf16x8*)&Vf[kt][c][1][lane * 8];
                O0 = __builtin_amdgcn_mfma_f32_16x16x32_bf16(pf, v0, O0, 0, 0, 0);
                O1 = __builtin_amdgcn_mfma_f32_16x16x32_bf16(pf, v1, O1, 0, 0, 0);
            }
        }
    }

    // reduce l across the 16 lanes of each row (once)
    #pragma unroll
    for (int msk = 1; msk < 16; msk <<= 1)
        #pragma unroll
        for (int r = 0; r < 4; r++)
            l_acc[r] += __shfl_xor(l_acc[r], msk, 16);

    #pragma unroll
    for (int r = 0; r < 4; r++) {
        const int i = i0 + l4 * 4 + r;
        unsigned short* crow = &Opart[((size_t)(z * 32 + bh) * NN + i) * 32];
        crow[l16]      = f2bf(O0[r]);
        crow[16 + l16] = f2bf(O1[r]);
        if (l16 == 0)
            lpart[(size_t)(z * 32 + bh) * NN + i] = l_acc[r];
    }
}

// ---------------------------------------------------------------------------
// K4: mega-fused post chain (16-row strips, 1024 threads). Fragment-layout
// weights (1 KB/instr streams). Split-K combine now x2. Cross-wave LN sums
// laid out [l4][r][16][2] and read with ds_read_b128 (4x fewer LDS instrs).
// ---------------------------------------------------------------------------
__global__ __launch_bounds__(1024)
void post_kernel(const unsigned short* __restrict__ Opart, const float* __restrict__ lpart,
                 const unsigned short* __restrict__ outwf,
                 const float* __restrict__ out_b, const float* __restrict__ embed,
                 const float* __restrict__ g1, const float* __restrict__ beta1,
                 const unsigned short* __restrict__ w1f, const float* __restrict__ b1,
                 const unsigned short* __restrict__ w2f, const float* __restrict__ b2,
                 const float* __restrict__ g2, const float* __restrict__ beta2,
                 float* __restrict__ out) {
    __shared__ float Lh[16][8];
    __shared__ unsigned short cs[16][264];
    __shared__ unsigned short xs[16][264];
    __shared__ unsigned short fs[16][1032];
    __shared__ float sums[4][4][16][2];    // [quad][r][wave][{s,q}]

    const int tid = threadIdx.x;
    const int w = tid >> 6, lane = tid & 63;
    const int l16 = lane & 15, l4 = lane >> 4;
    const int m0 = blockIdx.x * 16;
    const int b = m0 >> 10;                  // strip never crosses batch

    // ---- step 1: per-(row,head) 1/l table ----
    if (tid < 128) {
        const int row = tid >> 3, h = tid & 7;
        const int i = (m0 + row) & 1023;
        const int rowA = ((b * 8 + h) << 10) + i;
        Lh[row][h] = 1.0f / (lpart[rowA] + lpart[32768 + rowA]);
    }
    __syncthreads();

    // ---- step 2: combine bf16 Opart -> cs (512 threads, 8 d's each) ----
    if (tid < 512) {
        const int row = tid >> 5;            // 0..15
        const int d0 = (tid & 31) * 8;       // 0..248
        const int h = d0 >> 5;
        const int dd = d0 & 31;
        const int i = (m0 + row) & 1023;
        const int rowA = ((b * 8 + h) << 10) + i;
        float s[8] = {};
        #pragma unroll
        for (int z = 0; z < 2; z++) {
            bf16x8 u = *(const bf16x8*)&Opart[((size_t)(z * 32768 + rowA)) * 32 + dd];
            #pragma unroll
            for (int j = 0; j < 8; j++) s[j] += bf2f((unsigned short)u[j]);
        }
        const float li = Lh[row][h];
        #pragma unroll
        for (int j = 0; j < 8; j++)
            cs[row][d0 + j] = f2bf(s[j] * li);
    }
    __syncthreads();

    // ---- phase A: out-proj (wave owns 16 cols; 2 k-chains; frag weights) ----
    const int cA = w * 16 + l16;
    f32x4 a0 = {}, a1 = {};
    {
        const unsigned short* ofr = &outwf[(size_t)w * 8 * 512 + lane * 8];
        #pragma unroll
        for (int kk = 0; kk < 4; kk++) {
            const int k0 = kk * 32, k1 = 128 + kk * 32;
            bf16x8 x0 = *(const bf16x8*)&cs[l16][k0 + l4 * 8];
            bf16x8 b0 = *(const bf16x8*)&ofr[kk * 512];
            bf16x8 x1 = *(const bf16x8*)&cs[l16][k1 + l4 * 8];
            bf16x8 b1v = *(const bf16x8*)&ofr[(4 + kk) * 512];
            a0 = __builtin_amdgcn_mfma_f32_16x16x32_bf16(x0, b0, a0, 0, 0, 0);
            a1 = __builtin_amdgcn_mfma_f32_16x16x32_bf16(x1, b1v, a1, 0, 0, 0);
        }
    }
    float xv[4];
    {
        float s_r[4] = {0.f, 0.f, 0.f, 0.f}, q_r[4] = {0.f, 0.f, 0.f, 0.f};
        const float bs = out_b[cA];
        #pragma unroll
        for (int r = 0; r < 4; r++) {
            const int m = m0 + l4 * 4 + r;
            const float t = a0[r] + a1[r] + bs + embed[(size_t)m * D_MODEL + cA];
            xv[r] = t; s_r[r] += t; q_r[r] += t * t;
        }
        #pragma unroll
        for (int msk = 1; msk < 16; msk <<= 1)
            #pragma unroll
            for (int r = 0; r < 4; r++) {
                s_r[r] += __shfl_xor(s_r[r], msk, 16);
                q_r[r] += __shfl_xor(q_r[r], msk, 16);
            }
        if (l16 == 0)
            #pragma unroll
            for (int r = 0; r < 4; r++) {
                sums[l4][r][w][0] = s_r[r];
                sums[l4][r][w][1] = q_r[r];
            }
    }
    __syncthreads();
    #pragma unroll
    for (int r = 0; r < 4; r++) {
        const float* sp = &sums[l4][r][0][0];
        float s = 0.f, q = 0.f;
        #pragma unroll
        for (int ww = 0; ww < 8; ww++) {
            f32x4 v = *(const f32x4*)&sp[ww * 4];
            s += v[0] + v[2]; q += v[1] + v[3];
        }
        const float mu = s * (1.0f / D_MODEL);
        const float var = q * (1.0f / D_MODEL) - mu * mu;
        const float rstd = rsqrtf(var + LN_EPS);
        const float ov = (xv[r] - mu) * rstd * g1[cA] + beta1[cA];
        xv[r] = ov;                      // keep fp32 x for final residual
        xs[l4 * 4 + r][cA] = f2bf(ov);
    }
    __syncthreads();

    // ---- phase B: ffn1 relu (wave owns 64 ffn cols; frag weights, dbuf) ----
    f32x4 accB[4] = {};
    {
        const unsigned short* wfr = &w1f[(size_t)(w * 4) * 8 * 512 + lane * 8];
        bf16x8 wf[4], wfn[4];
        #pragma unroll
        for (int j = 0; j < 4; j++)
            wf[j] = *(const bf16x8*)&wfr[(size_t)j * 8 * 512];
        #pragma unroll
        for (int kk = 0; kk < 8; kk++) {
            if (kk < 7) {
                #pragma unroll
                for (int j = 0; j < 4; j++)
                    wfn[j] = *(const bf16x8*)&wfr[((size_t)j * 8 + kk + 1) * 512];
            }
            bf16x8 a = *(const bf16x8*)&xs[l16][kk * 32 + l4 * 8];
            #pragma unroll
            for (int j = 0; j < 4; j++)
                accB[j] = __builtin_amdgcn_mfma_f32_16x16x32_bf16(a, wf[j], accB[j], 0, 0, 0);
            if (kk < 7) {
                #pragma unroll
                for (int j = 0; j < 4; j++) wf[j] = wfn[j];
            }
        }
    }
    #pragma unroll
    for (int j = 0; j < 4; j++) {
        const int fc = w * 64 + j * 16 + l16;
        const float bs = b1[fc];
        #pragma unroll
        for (int r = 0; r < 4; r++)
            fs[l4 * 4 + r][fc] = f2bf(fmaxf(accB[j][r] + bs, 0.f));
    }
    __syncthreads();

    // ---- phase C: ffn2 + residual + LN2 (wave owns 16 cols; frag weights) ----
    f32x4 c0 = {}, c1 = {};
    {
        const unsigned short* wfr = &w2f[(size_t)w * 32 * 512 + lane * 8];
        bf16x8 wb0 = *(const bf16x8*)&wfr[0];
        bf16x8 wb1 = *(const bf16x8*)&wfr[16 * 512];
        #pragma unroll
        for (int kk = 0; kk < 16; kk++) {
            const int k0 = kk * 32, k1 = 512 + kk * 32;
            bf16x8 cur0 = wb0, cur1 = wb1;
            if (kk < 15) {
                wb0 = *(const bf16x8*)&wfr[(size_t)(kk + 1) * 512];
                wb1 = *(const bf16x8*)&wfr[(size_t)(16 + kk + 1) * 512];
            }
            bf16x8 f0 = *(const bf16x8*)&fs[l16][k0 + l4 * 8];
            bf16x8 f1 = *(const bf16x8*)&fs[l16][k1 + l4 * 8];
            c0 = __builtin_amdgcn_mfma_f32_16x16x32_bf16(f0, cur0, c0, 0, 0, 0);
            c1 = __builtin_amdgcn_mfma_f32_16x16x32_bf16(f1, cur1, c1, 0, 0, 0);
        }
    }
    float v2[4];
    {
        float s_r[4] = {0.f, 0.f, 0.f, 0.f}, q_r[4] = {0.f, 0.f, 0.f, 0.f};
        const float bs = b2[cA];
        #pragma unroll
        for (int r = 0; r < 4; r++) {
            const float t = c0[r] + c1[r] + bs + xv[r];
            v2[r] = t; s_r[r] += t; q_r[r] += t * t;
        }
        #pragma unroll
        for (int msk = 1; msk < 16; msk <<= 1)
            #pragma unroll
            for (int r = 0; r < 4; r++) {
                s_r[r] += __shfl_xor(s_r[r], msk, 16);
                q_r[r] += __shfl_xor(q_r[r], msk, 16);
            }
        if (l16 == 0)
            #pragma unroll
            for (int r = 0; r < 4; r++) {
                sums[l4][r][w][0] = s_r[r];
                sums[l4][r][w][1] = q_r[r];
            }
    }
    __syncthreads();
    #pragma unroll
    for (int r = 0; r < 4; r++) {
        const float* sp = &sums[l4][r][0][0];
        float s = 0.f, q = 0.f;
        #pragma unroll
        for (int ww = 0; ww < 8; ww++) {
            f32x4 v = *(const f32x4*)&sp[ww * 4];
            s += v[0] + v[2]; q += v[1] + v[3];
        }
        const float mu = s * (1.0f / D_MODEL);
        const float var = q * (1.0f / D_MODEL) - mu * mu;
        const float rstd = rsqrtf(var + LN_EPS);
        const int m = m0 + l4 * 4 + r;
        out[(size_t)m * D_MODEL + cA] = (v2[r] - mu) * rstd * g2[cA] + beta2[cA];
    }
}

// ---------------------------------------------------------------------------
// launch
// ---------------------------------------------------------------------------
extern "C" void kernel_launch(void* const* d_in, const int* in_sizes, int n_in,
                              void* d_out, int out_size, void* d_ws, size_t ws_size,
                              hipStream_t stream) {
    const float* embed     = (const float*)d_in[0];
    const float* dist      = (const float*)d_in[2];
    const float* query_pos = (const float*)d_in[3];
    const float* in_proj_w = (const float*)d_in[4];
    const float* in_proj_b = (const float*)d_in[5];
    const float* out_w     = (const float*)d_in[6];
    const float* out_b     = (const float*)d_in[7];
    const float* tau_w     = (const float*)d_in[8];
    const float* tau_b     = (const float*)d_in[9];
    const float* w1        = (const float*)d_in[10];
    const float* b1        = (const float*)d_in[11];
    const float* w2        = (const float*)d_in[12];
    const float* b2        = (const float*)d_in[13];
    const float* g1        = (const float*)d_in[14];
    const float* beta1     = (const float*)d_in[15];
    const float* g2        = (const float*)d_in[16];
    const float* beta2     = (const float*)d_in[17];
    float* out = (float*)d_out;

    char* ws = (char*)d_ws;
    const size_t MB = 1024 * 1024;
    const size_t KB = 1024;
    unsigned short* emb_bf  = (unsigned short*)(ws);                      // 2 MB
    unsigned short* qk_bf   = (unsigned short*)(ws + 2 * MB);             // 2 MB
    unsigned short* qb      = (unsigned short*)(ws + 4 * MB);             // 2 MB
    unsigned short* kb      = (unsigned short*)(ws + 6 * MB);             // 2 MB
    unsigned short* vbT     = (unsigned short*)(ws + 8 * MB);             // 2 MB
    float*          taub    = (float*)(ws + 10 * MB);                     // 128 KB
    unsigned short* inw_bf  = (unsigned short*)(ws + 11 * MB);            // 384 KB
    unsigned short* outwf   = (unsigned short*)(ws + 11 * MB + 512 * KB); // 128 KB (frag)
    unsigned short* w1f     = (unsigned short*)(ws + 12 * MB);            // 512 KB (frag)
    unsigned short* w2f     = (unsigned short*)(ws + 12 * MB + 512 * KB); // 512 KB (frag)
    unsigned short* taupad  = (unsigned short*)(ws + 13 * MB);            // 32 KB
    unsigned short* Opart   = (unsigned short*)(ws + 14 * MB);            // 4 MB bf16 (z=2)
    float*          lpart   = (float*)(ws + 22 * MB);                     // 256 KB

    // K1: fused prep (activations + row-major inw + frag-layout outw/w1/w2)
    prep_all_kernel<<<dim3(1520), dim3(256), 0, stream>>>(
        (const float4*)embed, (const float4*)query_pos,
        (ushort4*)emb_bf, (ushort4*)qk_bf,
        (const float4*)in_proj_w, (ushort4*)inw_bf,
        out_w, w1, w2, outwf, w1f, w2f,
        (const float4*)tau_w, (ushort4*)taupad);

    // K2: qkv + tau MFMA GEMM (q,tau pre-scaled for exp2 path)
    qkv_mfma_kernel<<<dim3(13, M_TOT / 64), dim3(256), 0, stream>>>(
        qk_bf, emb_bf, inw_bf, taupad, in_proj_b, tau_b, qb, kb, vbT, taub);

    // K3: flash MFMA attention v3, split-K x2 (two-half staging) -> partials
    attn_mfma_kernel<<<dim3(NN / 64, BB * N_HEADS, 2), dim3(256), 0, stream>>>(
        qb, kb, vbT, taub, dist, Opart, lpart);

    // K4: mega-fused combine + out-proj + LN1 + ffn1 + ffn2 + LN2 (16 waves)
    post_kernel<<<dim3(M_TOT / 16), dim3(1024), 0, stream>>>(
        Opart, lpart, outwf, out_b, embed, g1, beta1,
        w1f, b1, w2f, b2, g2, beta2, out);
}

// Round 15
// 163.915 us; speedup vs baseline: 1.0335x; 1.0335x over previous
//
#include <hip/hip_runtime.h>
#include <math.h>

#define D_MODEL 256
#define N_HEADS 8
#define HEAD_DIM 32
#define D_FFN   1024
#define BB      4
#define NN      1024
#define M_TOT   (BB * NN)     // 4096 rows
#define LN_EPS  1e-5f

// scale = 1/sqrt(32); baked into qb:  scale * log2(e)
#define QSCALE_LOG2E 0.2550348612f
#define LOG2E        1.4426950408889634f

typedef float f32x4 __attribute__((ext_vector_type(4)));
typedef short bf16x8 __attribute__((ext_vector_type(8)));

__device__ __forceinline__ unsigned short f2bf(float f) {
    unsigned int u = __float_as_uint(f);
    unsigned int r = (u + 0x7fffu + ((u >> 16) & 1u)) >> 16;
    return (unsigned short)r;
}
__device__ __forceinline__ ushort4 pack4(float4 v) {
    ushort4 o; o.x = f2bf(v.x); o.y = f2bf(v.y); o.z = f2bf(v.z); o.w = f2bf(v.w);
    return o;
}
__device__ __forceinline__ float fast_exp2(float x) {
#if __has_builtin(__builtin_amdgcn_exp2f)
    return __builtin_amdgcn_exp2f(x);
#else
    return exp2f(x);
#endif
}
__device__ __forceinline__ float bf2f(unsigned short s) {
    return __uint_as_float(((unsigned int)s) << 16);
}

// ---------------------------------------------------------------------------
// K1: fused prep.
//  blocks [0,1024):    emb_bf / qk_bf activations
//  blocks [1024,1216): inw fp32->bf16 (row-major, for qkv)
//  blocks [1216,1504): outw/w1/w2 -> WAVE-FRAGMENT layout bf16:
//                      frag[( n16*(K/32)+kk )*64 + lane]*8 where
//                      row = n16*16 + (lane&15), col = kk*32 + (lane>>4)*8.
//                      Makes every post weight load 1 KB contiguous/instr.
//  blocks [1504,1520): zero-padded tau tile
// ---------------------------------------------------------------------------
__global__ __launch_bounds__(256)
void prep_all_kernel(const float4* __restrict__ e, const float4* __restrict__ qp,
                     ushort4* __restrict__ ebf, ushort4* __restrict__ qkbf,
                     const float4* __restrict__ inw4, ushort4* __restrict__ o_inw,
                     const float* __restrict__ outw, const float* __restrict__ w1,
                     const float* __restrict__ w2,
                     unsigned short* __restrict__ o_outwf,
                     unsigned short* __restrict__ o_w1f,
                     unsigned short* __restrict__ o_w2f,
                     const float4* __restrict__ tauw, ushort4* __restrict__ o_taupad) {
    if (blockIdx.x < 1024) {
        int i = blockIdx.x * 256 + threadIdx.x;       // < 262144
        float4 ev = e[i], pv = qp[i];
        ebf[i] = pack4(ev);
        float4 s = make_float4(ev.x + pv.x, ev.y + pv.y, ev.z + pv.z, ev.w + pv.w);
        qkbf[i] = pack4(s);
    } else if (blockIdx.x < 1216) {
        int i = (blockIdx.x - 1024) * 256 + threadIdx.x;   // < 49152
        o_inw[i] = pack4(inw4[i]);
    } else if (blockIdx.x < 1504) {
        int fid = (blockIdx.x - 1216) * 256 + threadIdx.x; // < 73728
        const float* W; unsigned short* dst; int K;
        if (fid < 8192)       { W = outw; dst = o_outwf; K = 256; }
        else if (fid < 40960) { W = w1;   dst = o_w1f;   K = 256;  fid -= 8192; }
        else                  { W = w2;   dst = o_w2f;   K = 1024; fid -= 40960; }
        const int lane = fid & 63;
        const int t = fid >> 6;
        const int kk = t % (K / 32);
        const int n16 = t / (K / 32);
        const int row = n16 * 16 + (lane & 15);
        const int col = kk * 32 + (lane >> 4) * 8;
        const float* src = &W[(size_t)row * K + col];
        float4 s0 = *(const float4*)src, s1 = *(const float4*)(src + 4);
        *(ushort4*)&dst[(size_t)fid * 8]     = pack4(s0);
        *(ushort4*)&dst[(size_t)fid * 8 + 4] = pack4(s1);
    } else {
        int q = (blockIdx.x - 1504) * 256 + threadIdx.x;   // < 4096
        if (q < 512) o_taupad[q] = pack4(tauw[q]);
        else { ushort4 z = {0, 0, 0, 0}; o_taupad[q] = z; }
    }
}

// ---------------------------------------------------------------------------
// K2: qkv+tau register-direct MFMA GEMM (bf16 pre-staged A).
// q stored pre-scaled by scale*log2e; tau pre-scaled by log2e (exp2 path).
// ---------------------------------------------------------------------------
__global__ __launch_bounds__(256)
void qkv_mfma_kernel(const unsigned short* __restrict__ qk_bf,
                     const unsigned short* __restrict__ emb_bf,
                     const unsigned short* __restrict__ inw_bf,
                     const unsigned short* __restrict__ taupad,
                     const float* __restrict__ in_proj_b, const float* __restrict__ tau_b,
                     unsigned short* __restrict__ qb, unsigned short* __restrict__ kb,
                     unsigned short* __restrict__ vbT, float* __restrict__ taub) {
    const int w    = threadIdx.x >> 6;
    const int lane = threadIdx.x & 63;
    const int l16 = lane & 15, l4 = lane >> 4;
    const int n0 = blockIdx.x * 64;
    const int m0 = blockIdx.y * 64;
    const int wm = (w >> 1) * 32, wn = (w & 1) * 32;

    const unsigned short* A = (blockIdx.x < 8) ? qk_bf : emb_bf;
    const unsigned short* W0 = (n0 < 768) ? &inw_bf[(size_t)(n0 + wn + l16) * D_MODEL]
                                          : &taupad[(size_t)(wn + l16) * D_MODEL];
    const unsigned short* Ar0 = &A[(size_t)(m0 + wm + l16) * D_MODEL];

    f32x4 acc[2][2] = {};
    #pragma unroll
    for (int k0 = 0; k0 < D_MODEL; k0 += 32) {
        bf16x8 a0 = *(const bf16x8*)&Ar0[k0 + l4 * 8];
        bf16x8 a1 = *(const bf16x8*)&Ar0[16 * D_MODEL + k0 + l4 * 8];
        bf16x8 b0 = *(const bf16x8*)&W0[k0 + l4 * 8];
        bf16x8 b1 = *(const bf16x8*)&W0[16 * D_MODEL + k0 + l4 * 8];
        acc[0][0] = __builtin_amdgcn_mfma_f32_16x16x32_bf16(a0, b0, acc[0][0], 0, 0, 0);
        acc[0][1] = __builtin_amdgcn_mfma_f32_16x16x32_bf16(a0, b1, acc[0][1], 0, 0, 0);
        acc[1][0] = __builtin_amdgcn_mfma_f32_16x16x32_bf16(a1, b0, acc[1][0], 0, 0, 0);
        acc[1][1] = __builtin_amdgcn_mfma_f32_16x16x32_bf16(a1, b1, acc[1][1], 0, 0, 0);
    }

    #pragma unroll
    for (int i = 0; i < 2; i++) {
        #pragma unroll
        for (int j = 0; j < 2; j++) {
            #pragma unroll
            for (int r = 0; r < 4; r++) {
                const int m = m0 + wm + i * 16 + l4 * 4 + r;
                const int b = m >> 10, nrow = m & 1023;
                const int c = n0 + wn + j * 16 + l16;
                float v = acc[i][j][r];
                if (c < 256) {
                    v = (v + in_proj_b[c]) * QSCALE_LOG2E;   // pre-scaled q
                    int h = c >> 5, d = c & 31;
                    qb[((size_t)(b * N_HEADS + h) * NN + nrow) * HEAD_DIM + d] = f2bf(v);
                } else if (c < 512) {
                    v += in_proj_b[c];
                    int cc = c - 256; int h = cc >> 5, d = cc & 31;
                    kb[((size_t)(b * N_HEADS + h) * NN + nrow) * HEAD_DIM + d] = f2bf(v);
                } else if (c < 768) {
                    v += in_proj_b[c];
                    int cc = c - 512; int h = cc >> 5, d = cc & 31;
                    vbT[((size_t)(b * N_HEADS + h) * HEAD_DIM + d) * NN + nrow] = f2bf(v);
                } else if (c < 776) {
                    v = (v + tau_b[c - 768]) * LOG2E;        // pre-scaled tau
                    taub[(size_t)(b * N_HEADS + (c - 768)) * NN + nrow] = v;
                }
            }
        }
    }
}

// ---------------------------------------------------------------------------
// K3: flash MFMA attention v2 (R9/R12 version). Split-K x4; K/V staged per
// block in LDS (4x dedup); interleaved key mapping -> one float4 dist load
// per r; unnormalized exp2; bf16 Opart.
// ---------------------------------------------------------------------------
__global__ __launch_bounds__(256)
void attn_mfma_kernel(const unsigned short* __restrict__ qb,
                      const unsigned short* __restrict__ kb,
                      const unsigned short* __restrict__ vbT,
                      const float* __restrict__ taub,
                      const float* __restrict__ dist,
                      unsigned short* __restrict__ Opart,
                      float* __restrict__ lpart) {
    __shared__ unsigned short Kf[4][4][512];       // [kt][s][lane*8]       16 KB
    __shared__ unsigned short Vf[4][2][2][512];    // [kt][c][half][lane*8] 16 KB
    __shared__ unsigned short Plds[4][16 * 72];    // per-wave P            9 KB
    const int w    = threadIdx.x >> 6;
    const int lane = threadIdx.x & 63;
    const int l16  = lane & 15;
    const int l4   = lane >> 4;
    const int bh = blockIdx.y;
    const int b = bh >> 3;
    const int z = blockIdx.z;
    const int i0 = blockIdx.x * 64 + w * 16;
    const int jbase = z * 256;

    // ---- stage K/V fragments: wave w loads key-tile kt = w ----
    {
        const int kt = w;
        const unsigned short* kb_z = &kb[((size_t)bh * NN + jbase + kt * 64) * HEAD_DIM];
        #pragma unroll
        for (int s = 0; s < 4; s++) {
            bf16x8 kv = *(const bf16x8*)&kb_z[(size_t)(l16 * 4 + s) * HEAD_DIM + l4 * 8];
            *(bf16x8*)&Kf[kt][s][lane * 8] = kv;
        }
        const unsigned short* vb_z = &vbT[(size_t)bh * HEAD_DIM * NN + jbase + kt * 64];
        #pragma unroll
        for (int c = 0; c < 2; c++)
            #pragma unroll
            for (int h2 = 0; h2 < 2; h2++) {
                bf16x8 vv = *(const bf16x8*)&vb_z[(size_t)(h2 * 16 + l16) * NN + c * 32 + l4 * 8];
                *(bf16x8*)&Vf[kt][c][h2][lane * 8] = vv;
            }
    }

    const f32x4 zero = {0.f, 0.f, 0.f, 0.f};
    bf16x8 qf = *(const bf16x8*)&qb[((size_t)bh * NN + i0 + l16) * HEAD_DIM + l4 * 8];
    float tau_r[4];
    const float* drow[4];
    #pragma unroll
    for (int r = 0; r < 4; r++) {
        tau_r[r] = taub[(size_t)bh * NN + i0 + l4 * 4 + r];
        drow[r] = &dist[((size_t)b * NN + i0 + l4 * 4 + r) * NN + jbase];
    }
    float l_acc[4] = {0.f, 0.f, 0.f, 0.f};
    f32x4 O0 = zero, O1 = zero;
    unsigned short* pw = &Plds[w][0];

    __syncthreads();

    for (int kt = 0; kt < 4; kt++) {
        const int j0 = kt * 64;
        // dist: one float4 per r (keys l16*4 .. +3)
        f32x4 dd4[4];
        #pragma unroll
        for (int r = 0; r < 4; r++)
            dd4[r] = *(const f32x4*)&drow[r][j0 + l16 * 4];

        float parr[4][4];
        #pragma unroll
        for (int s = 0; s < 4; s++) {
            bf16x8 kfr = *(const bf16x8*)&Kf[kt][s][lane * 8];
            f32x4 S = __builtin_amdgcn_mfma_f32_16x16x32_bf16(qf, kfr, zero, 0, 0, 0);
            #pragma unroll
            for (int r = 0; r < 4; r++) {
                const float p = fast_exp2(S[r] + dd4[r][s] * tau_r[r]);
                parr[s][r] = p;
                l_acc[r] += p;
            }
        }

        // P: key for (s, lane l16) is j0 + l16*4 + s -> 4 consecutive u16
        #pragma unroll
        for (int r = 0; r < 4; r++) {
            ushort4 pk;
            pk.x = f2bf(parr[0][r]); pk.y = f2bf(parr[1][r]);
            pk.z = f2bf(parr[2][r]); pk.w = f2bf(parr[3][r]);
            *(ushort4*)&pw[(l4 * 4 + r) * 72 + l16 * 4] = pk;
        }
        asm volatile("s_waitcnt lgkmcnt(0)" ::: "memory");  // wave-local RAW drain
        #pragma unroll
        for (int c = 0; c < 2; c++) {
            bf16x8 pf = *(const bf16x8*)&pw[l16 * 72 + c * 32 + l4 * 8];
            bf16x8 v0 = *(const bf16x8*)&Vf[kt][c][0][lane * 8];
            bf16x8 v1 = *(const bf16x8*)&Vf[kt][c][1][lane * 8];
            O0 = __builtin_amdgcn_mfma_f32_16x16x32_bf16(pf, v0, O0, 0, 0, 0);
            O1 = __builtin_amdgcn_mfma_f32_16x16x32_bf16(pf, v1, O1, 0, 0, 0);
        }
    }

    // reduce l across the 16 lanes of each row (once)
    #pragma unroll
    for (int msk = 1; msk < 16; msk <<= 1)
        #pragma unroll
        for (int r = 0; r < 4; r++)
            l_acc[r] += __shfl_xor(l_acc[r], msk, 16);

    #pragma unroll
    for (int r = 0; r < 4; r++) {
        const int i = i0 + l4 * 4 + r;
        unsigned short* crow = &Opart[((size_t)(z * 32 + bh) * NN + i) * 32];
        crow[l16]      = f2bf(O0[r]);
        crow[16 + l16] = f2bf(O1[r]);
        if (l16 == 0)
            lpart[(size_t)(z * 32 + bh) * NN + i] = l_acc[r];
    }
}

// ---------------------------------------------------------------------------
// K4: mega-fused post chain (16-row strips, 1024 threads). Weights read in
// FRAGMENT layout: every weight load is a fully-coalesced 1 KB/instruction
// stream (frag block = 512 bf16 = 64 lanes x 8).
// ---------------------------------------------------------------------------
__global__ __launch_bounds__(1024)
void post_kernel(const unsigned short* __restrict__ Opart, const float* __restrict__ lpart,
                 const unsigned short* __restrict__ outwf,
                 const float* __restrict__ out_b, const float* __restrict__ embed,
                 const float* __restrict__ g1, const float* __restrict__ beta1,
                 const unsigned short* __restrict__ w1f, const float* __restrict__ b1,
                 const unsigned short* __restrict__ w2f, const float* __restrict__ b2,
                 const float* __restrict__ g2, const float* __restrict__ beta2,
                 float* __restrict__ out) {
    __shared__ float Lh[16][8];
    __shared__ unsigned short cs[16][264];
    __shared__ unsigned short xs[16][264];
    __shared__ unsigned short fs[16][1032];
    __shared__ float sums[16][4][4][2];

    const int tid = threadIdx.x;
    const int w = tid >> 6, lane = tid & 63;
    const int l16 = lane & 15, l4 = lane >> 4;
    const int m0 = blockIdx.x * 16;
    const int b = m0 >> 10;                  // strip never crosses batch

    // ---- step 1: per-(row,head) 1/l table ----
    if (tid < 128) {
        const int row = tid >> 3, h = tid & 7;
        const int i = (m0 + row) & 1023;
        const int rowA = ((b * 8 + h) << 10) + i;
        float l = 0.f;
        #pragma unroll
        for (int z = 0; z < 4; z++) l += lpart[z * 32768 + rowA];
        Lh[row][h] = 1.0f / l;
    }
    __syncthreads();

    // ---- step 2: combine bf16 Opart -> cs (512 threads, 8 d's each) ----
    if (tid < 512) {
        const int row = tid >> 5;            // 0..15
        const int d0 = (tid & 31) * 8;       // 0..248
        const int h = d0 >> 5;
        const int dd = d0 & 31;
        const int i = (m0 + row) & 1023;
        const int rowA = ((b * 8 + h) << 10) + i;
        float s[8] = {};
        #pragma unroll
        for (int z = 0; z < 4; z++) {
            bf16x8 u = *(const bf16x8*)&Opart[((size_t)(z * 32768 + rowA)) * 32 + dd];
            #pragma unroll
            for (int j = 0; j < 8; j++) s[j] += bf2f((unsigned short)u[j]);
        }
        const float li = Lh[row][h];
        #pragma unroll
        for (int j = 0; j < 8; j++)
            cs[row][d0 + j] = f2bf(s[j] * li);
    }
    __syncthreads();

    // ---- phase A: out-proj (wave owns 16 cols; 2 k-chains; frag weights) ----
    const int cA = w * 16 + l16;
    f32x4 a0 = {}, a1 = {};
    {
        const unsigned short* ofr = &outwf[(size_t)w * 8 * 512 + lane * 8];
        #pragma unroll
        for (int kk = 0; kk < 4; kk++) {
            const int k0 = kk * 32, k1 = 128 + kk * 32;
            bf16x8 x0 = *(const bf16x8*)&cs[l16][k0 + l4 * 8];
            bf16x8 b0 = *(const bf16x8*)&ofr[kk * 512];
            bf16x8 x1 = *(const bf16x8*)&cs[l16][k1 + l4 * 8];
            bf16x8 b1v = *(const bf16x8*)&ofr[(4 + kk) * 512];
            a0 = __builtin_amdgcn_mfma_f32_16x16x32_bf16(x0, b0, a0, 0, 0, 0);
            a1 = __builtin_amdgcn_mfma_f32_16x16x32_bf16(x1, b1v, a1, 0, 0, 0);
        }
    }
    float xv[4];
    {
        float s_r[4] = {0.f, 0.f, 0.f, 0.f}, q_r[4] = {0.f, 0.f, 0.f, 0.f};
        const float bs = out_b[cA];
        #pragma unroll
        for (int r = 0; r < 4; r++) {
            const int m = m0 + l4 * 4 + r;
            const float t = a0[r] + a1[r] + bs + embed[(size_t)m * D_MODEL + cA];
            xv[r] = t; s_r[r] += t; q_r[r] += t * t;
        }
        #pragma unroll
        for (int msk = 1; msk < 16; msk <<= 1)
            #pragma unroll
            for (int r = 0; r < 4; r++) {
                s_r[r] += __shfl_xor(s_r[r], msk, 16);
                q_r[r] += __shfl_xor(q_r[r], msk, 16);
            }
        if (l16 == 0)
            #pragma unroll
            for (int r = 0; r < 4; r++) {
                sums[w][l4][r][0] = s_r[r];
                sums[w][l4][r][1] = q_r[r];
            }
    }
    __syncthreads();
    #pragma unroll
    for (int r = 0; r < 4; r++) {
        float s = 0.f, q = 0.f;
        #pragma unroll
        for (int ww = 0; ww < 16; ww++) { s += sums[ww][l4][r][0]; q += sums[ww][l4][r][1]; }
        const float mu = s * (1.0f / D_MODEL);
        const float var = q * (1.0f / D_MODEL) - mu * mu;
        const float rstd = rsqrtf(var + LN_EPS);
        const float ov = (xv[r] - mu) * rstd * g1[cA] + beta1[cA];
        xv[r] = ov;                      // keep fp32 x for final residual
        xs[l4 * 4 + r][cA] = f2bf(ov);
    }
    __syncthreads();

    // ---- phase B: ffn1 relu (wave owns 64 ffn cols; frag weights, dbuf) ----
    f32x4 accB[4] = {};
    {
        // frag base for (n16 = w*4+j, kk): w1f[((w*4+j)*8 + kk)*512 + lane*8]
        const unsigned short* wfr = &w1f[(size_t)(w * 4) * 8 * 512 + lane * 8];
        bf16x8 wf[4], wfn[4];
        #pragma unroll
        for (int j = 0; j < 4; j++)
            wf[j] = *(const bf16x8*)&wfr[(size_t)j * 8 * 512];
        #pragma unroll
        for (int kk = 0; kk < 8; kk++) {
            if (kk < 7) {
                #pragma unroll
                for (int j = 0; j < 4; j++)
                    wfn[j] = *(const bf16x8*)&wfr[((size_t)j * 8 + kk + 1) * 512];
            }
            bf16x8 a = *(const bf16x8*)&xs[l16][kk * 32 + l4 * 8];
            #pragma unroll
            for (int j = 0; j < 4; j++)
                accB[j] = __builtin_amdgcn_mfma_f32_16x16x32_bf16(a, wf[j], accB[j], 0, 0, 0);
            if (kk < 7) {
                #pragma unroll
                for (int j = 0; j < 4; j++) wf[j] = wfn[j];
            }
        }
    }
    #pragma unroll
    for (int j = 0; j < 4; j++) {
        const int fc = w * 64 + j * 16 + l16;
        const float bs = b1[fc];
        #pragma unroll
        for (int r = 0; r < 4; r++)
            fs[l4 * 4 + r][fc] = f2bf(fmaxf(accB[j][r] + bs, 0.f));
    }
    __syncthreads();

    // ---- phase C: ffn2 + residual + LN2 (wave owns 16 cols; frag weights) ----
    f32x4 c0 = {}, c1 = {};
    {
        // frag base for (n16 = w, kk_g = half*16 + kk): w2f[(w*32 + kk_g)*512 + lane*8]
        const unsigned short* wfr = &w2f[(size_t)w * 32 * 512 + lane * 8];
        bf16x8 wb0 = *(const bf16x8*)&wfr[0];
        bf16x8 wb1 = *(const bf16x8*)&wfr[16 * 512];
        #pragma unroll
        for (int kk = 0; kk < 16; kk++) {
            const int k0 = kk * 32, k1 = 512 + kk * 32;
            bf16x8 cur0 = wb0, cur1 = wb1;
            if (kk < 15) {
                wb0 = *(const bf16x8*)&wfr[(size_t)(kk + 1) * 512];
                wb1 = *(const bf16x8*)&wfr[(size_t)(16 + kk + 1) * 512];
            }
            bf16x8 f0 = *(const bf16x8*)&fs[l16][k0 + l4 * 8];
            bf16x8 f1 = *(const bf16x8*)&fs[l16][k1 + l4 * 8];
            c0 = __builtin_amdgcn_mfma_f32_16x16x32_bf16(f0, cur0, c0, 0, 0, 0);
            c1 = __builtin_amdgcn_mfma_f32_16x16x32_bf16(f1, cur1, c1, 0, 0, 0);
        }
    }
    float v2[4];
    {
        float s_r[4] = {0.f, 0.f, 0.f, 0.f}, q_r[4] = {0.f, 0.f, 0.f, 0.f};
        const float bs = b2[cA];
        #pragma unroll
        for (int r = 0; r < 4; r++) {
            const float t = c0[r] + c1[r] + bs + xv[r];
            v2[r] = t; s_r[r] += t; q_r[r] += t * t;
        }
        #pragma unroll
        for (int msk = 1; msk < 16; msk <<= 1)
            #pragma unroll
            for (int r = 0; r < 4; r++) {
                s_r[r] += __shfl_xor(s_r[r], msk, 16);
                q_r[r] += __shfl_xor(q_r[r], msk, 16);
            }
        if (l16 == 0)
            #pragma unroll
            for (int r = 0; r < 4; r++) {
                sums[w][l4][r][0] = s_r[r];
                sums[w][l4][r][1] = q_r[r];
            }
    }
    __syncthreads();
    #pragma unroll
    for (int r = 0; r < 4; r++) {
        float s = 0.f, q = 0.f;
        #pragma unroll
        for (int ww = 0; ww < 16; ww++) { s += sums[ww][l4][r][0]; q += sums[ww][l4][r][1]; }
        const float mu = s * (1.0f / D_MODEL);
        const float var = q * (1.0f / D_MODEL) - mu * mu;
        const float rstd = rsqrtf(var + LN_EPS);
        const int m = m0 + l4 * 4 + r;
        out[(size_t)m * D_MODEL + cA] = (v2[r] - mu) * rstd * g2[cA] + beta2[cA];
    }
}

// ---------------------------------------------------------------------------
// launch
// ---------------------------------------------------------------------------
extern "C" void kernel_launch(void* const* d_in, const int* in_sizes, int n_in,
                              void* d_out, int out_size, void* d_ws, size_t ws_size,
                              hipStream_t stream) {
    const float* embed     = (const float*)d_in[0];
    const float* dist      = (const float*)d_in[2];
    const float* query_pos = (const float*)d_in[3];
    const float* in_proj_w = (const float*)d_in[4];
    const float* in_proj_b = (const float*)d_in[5];
    const float* out_w     = (const float*)d_in[6];
    const float* out_b     = (const float*)d_in[7];
    const float* tau_w     = (const float*)d_in[8];
    const float* tau_b     = (const float*)d_in[9];
    const float* w1        = (const float*)d_in[10];
    const float* b1        = (const float*)d_in[11];
    const float* w2        = (const float*)d_in[12];
    const float* b2        = (const float*)d_in[13];
    const float* g1        = (const float*)d_in[14];
    const float* beta1     = (const float*)d_in[15];
    const float* g2        = (const float*)d_in[16];
    const float* beta2     = (const float*)d_in[17];
    float* out = (float*)d_out;

    char* ws = (char*)d_ws;
    const size_t MB = 1024 * 1024;
    const size_t KB = 1024;
    unsigned short* emb_bf  = (unsigned short*)(ws);                      // 2 MB
    unsigned short* qk_bf   = (unsigned short*)(ws + 2 * MB);             // 2 MB
    unsigned short* qb      = (unsigned short*)(ws + 4 * MB);             // 2 MB
    unsigned short* kb      = (unsigned short*)(ws + 6 * MB);             // 2 MB
    unsigned short* vbT     = (unsigned short*)(ws + 8 * MB);             // 2 MB
    float*          taub    = (float*)(ws + 10 * MB);                     // 128 KB
    unsigned short* inw_bf  = (unsigned short*)(ws + 11 * MB);            // 384 KB
    unsigned short* outwf   = (unsigned short*)(ws + 11 * MB + 512 * KB); // 128 KB (frag)
    unsigned short* w1f     = (unsigned short*)(ws + 12 * MB);            // 512 KB (frag)
    unsigned short* w2f     = (unsigned short*)(ws + 12 * MB + 512 * KB); // 512 KB (frag)
    unsigned short* taupad  = (unsigned short*)(ws + 13 * MB);            // 32 KB
    unsigned short* Opart   = (unsigned short*)(ws + 14 * MB);            // 8 MB bf16
    float*          lpart   = (float*)(ws + 22 * MB);                     // 512 KB

    // K1: fused prep (activations + row-major inw + frag-layout outw/w1/w2)
    prep_all_kernel<<<dim3(1520), dim3(256), 0, stream>>>(
        (const float4*)embed, (const float4*)query_pos,
        (ushort4*)emb_bf, (ushort4*)qk_bf,
        (const float4*)in_proj_w, (ushort4*)inw_bf,
        out_w, w1, w2, outwf, w1f, w2f,
        (const float4*)tau_w, (ushort4*)taupad);

    // K2: qkv + tau MFMA GEMM (q,tau pre-scaled for exp2 path)
    qkv_mfma_kernel<<<dim3(13, M_TOT / 64), dim3(256), 0, stream>>>(
        qk_bf, emb_bf, inw_bf, taupad, in_proj_b, tau_b, qb, kb, vbT, taub);

    // K3: flash MFMA attention v2, split-K x4 -> bf16 partials
    attn_mfma_kernel<<<dim3(NN / 64, BB * N_HEADS, 4), dim3(256), 0, stream>>>(
        qb, kb, vbT, taub, dist, Opart, lpart);

    // K4: mega-fused combine + out-proj + LN1 + ffn1 + ffn2 + LN2 (16 waves)
    post_kernel<<<dim3(M_TOT / 16), dim3(1024), 0, stream>>>(
        Opart, lpart, outwf, out_b, embed, g1, beta1,
        w1f, b1, w2f, b2, g2, beta2, out);
}